// Round 11
// baseline (142.556 us; speedup 1.0000x reference)
//
#include <hip/hip_runtime.h>
#include <climits>
#include <stdint.h>

typedef unsigned int u32;
typedef unsigned long long u64;
typedef int v4i __attribute__((ext_vector_type(4)));

#define HH 1536
#define WW 2048
#define NPIX (HH*WW)        // 3145728
#define WSHIFT 11
#define WPR 64              // 32-bit words per row
#define SH 4                // rows per strip
#define NS 384              // strips (= strip-kernel grid)
#define RPR 32              // run slots per row
#define SLOTS (SH*RPR)      // 128
#define NCAP 768            // global node cap (~600 expected)
#define BSLOT 8             // staged boundary-run slots per side

#define GLD(p) __hip_atomic_load((p), __ATOMIC_RELAXED, __HIP_MEMORY_SCOPE_AGENT)

// ---------------- K1: threshold + pack via ballot (pure streaming read) ------
__global__ void k_flags(const float2* __restrict__ xv,
                        u64* __restrict__ combp64, u64* __restrict__ textp64,
                        int* __restrict__ ctrs) {
    int gid = blockIdx.x * 256 + threadIdx.x;
    float2 f = xv[gid];
    int tx = f.x > 0.4f;
    int cb = tx | (f.y > 0.4f);
    u64 bc = __ballot(cb);
    u64 bt = __ballot(tx);
    if ((threadIdx.x & 63) == 0) {
        combp64[gid >> 6] = bc;
        textp64[gid >> 6] = bt;
    }
    if (gid == 0) { ctrs[0] = 0; ctrs[1] = 0; }   // done, gcnt
}

// ---------------- LDS UF with path halving (R6 lesson) -----------------------
__device__ __forceinline__ int lfind_h(int* L, int x) {
    while (true) {
        int p = L[x];
        if (p == x) return x;
        int g = L[p];
        if (g == p) return p;
        L[x] = g;
        x = g;
    }
}

__device__ __forceinline__ void lmerge(int* L, int a, int b) {
    while (true) {
        a = lfind_h(L, a);
        b = lfind_h(L, b);
        if (a == b) return;
        if (a < b) { int s = a; a = b; b = s; }
        int old = atomicMin(&L[a], b);
        if (old == a) return;
        a = old;
    }
}

// ---------------- K2: 4-row strips (384 blocks) + staged-LDS final -----------
// One wave per row (wave spans the full 64-word row). Encoded maxima (>0,
// LDS 0-init identity): 2047-row, row+1, 2048-start, end+1.
__global__ __launch_bounds__(256) void k_stripf(
        const u32* __restrict__ combp, const u32* __restrict__ textp,
        u32* __restrict__ brun_se, int* __restrict__ brun_id,
        int* __restrict__ bcnt, u32* __restrict__ groots, int* __restrict__ ctrs,
        v4i* __restrict__ obb, int* __restrict__ oval) {
    __shared__ u32 sb[SH][RPR], eb[SH][RPR];
    __shared__ u32 rec[SLOTS];
    __shared__ int lab[SLOTS];
    __shared__ int a0[SLOTS], a1[SLOTS], a2[SLOTS], a3[SLOTS], atx[SLOTS];
    __shared__ int nodemap[SLOTS];
    __shared__ int nper[SH];
    __shared__ int wtot[4], woff[4];
    __shared__ int sBase, sLast;
    // final-phase staging (last block only; ~72 KB total keeps 2 blocks/CU)
    __shared__ u32 sse[NS * 2 * BSLOT];
    __shared__ int sid[NS * 2 * BSLOT];
    __shared__ int sbc[NS * 2];
    __shared__ int flab[NCAP];
    __shared__ int f0[NCAP], f1[NCAP], f2[NCAP], f3[NCAP], ftx2[NCAP], fpix[NCAP];

    int strip = blockIdx.x;
    int rbase = strip * SH;
    int t = threadIdx.x;
    int wv = t >> 6, l = t & 63;

    // ---- Phase 1: dilate + extract runs, one wave per row ----
    {
        int r = rbase + wv;
        int base = r * WPR + l;
        u32 c0 = combp[base];
        u32 cm = (r > 0)      ? combp[base - WPR] : 0u;
        u32 cp = (r < HH - 1) ? combp[base + WPR] : 0u;
        u32 v = c0 | cm | cp;
        u32 vl = __shfl_up(v, 1);   if (l == 0)  vl = 0;
        u32 vr = __shfl_down(v, 1); if (l == 63) vr = 0;
        u32 f = v | (v << 1) | (v >> 1) | (vl >> 31) | (vr << 31);
        u32 flw = __shfl_up(f, 1);   if (l == 0)  flw = 0;
        u32 frw = __shfl_down(f, 1); if (l == 63) frw = 0;
        u32 smask = f & ~((f << 1) | (flw >> 31));
        u32 emask = f & ~((f >> 1) | ((frw & 1u) << 31));
        int ns = __popc(smask), ne = __popc(emask);
        int is = ns, ie = ne;
        #pragma unroll
        for (int o = 1; o < 64; o <<= 1) {
            int a = __shfl_up(is, o); if (l >= o) is += a;
            int b = __shfl_up(ie, o); if (l >= o) ie += b;
        }
        int ks = is - ns, ke = ie - ne;
        u32 m = smask; int k = ks;
        while (m) { int b = __ffs(m) - 1; m &= m - 1; if (k < RPR) sb[wv][k] = (u32)(l * 32 + b); ++k; }
        m = emask; k = ke;
        while (m) { int b = __ffs(m) - 1; m &= m - 1; if (k < RPR) eb[wv][k] = (u32)(l * 32 + b); ++k; }
        int nr = min(__shfl(is, 63), RPR);
        if (l == 0) nper[wv] = nr;
        // per-run txt bit
        u32 tK = textp[base] & f;
        u32 txtm = 0;
        for (int kk = 0; kk < nr; ++kk) {
            int st = (int)sb[wv][kk], en = (int)eb[wv][kk];
            int lo = max(st - l * 32, 0), hi = min(en - l * 32, 31);
            u32 mask = 0;
            if (lo <= hi)
                mask = ((hi == 31) ? 0xFFFFFFFFu : ((1u << (hi + 1)) - 1u)) & ~((1u << lo) - 1u);
            int any = __any((tK & mask) != 0);
            txtm |= (any ? 1u : 0u) << kk;
        }
        if (l < nr)
            rec[wv * RPR + l] = sb[wv][l] | (eb[wv][l] << 11) | (((txtm >> l) & 1u) << 22);
    }
    if (t < SLOTS) {
        lab[t] = t; a0[t] = 0; a1[t] = 0; a2[t] = 0; a3[t] = 0; atx[t] = 0;
        nodemap[t] = -1;
    }
    __syncthreads();

    // ---- Phase 2: vertical merges (3 row pairs, two-pointer, all LDS) ----
    if (t < SH - 1) {
        int na = nper[t], nb = nper[t + 1];
        int i = 0, j = 0;
        while (i < na && j < nb) {
            u32 ra = rec[t * RPR + i], rb = rec[(t + 1) * RPR + j];
            int sa = ra & 2047, ea = (ra >> 11) & 2047;
            int sb2 = rb & 2047, eb2 = (rb >> 11) & 2047;
            if (sa <= eb2 && sb2 <= ea) lmerge(lab, t * RPR + i, (t + 1) * RPR + j);
            if (ea <= eb2) ++i; else ++j;
        }
    }
    __syncthreads();

    // ---- Phase 3: jump compression ----
    #pragma unroll
    for (int pass = 0; pass < 4; ++pass) {
        if (t < SLOTS) {
            int p = lab[t], g = lab[p];
            if (g != p) lab[t] = g;
        }
        __syncthreads();
    }

    // ---- Phase 4: fold runs into strip-root accumulators (LDS atomics) ----
    int occ = (t < SLOTS) && ((t & (RPR - 1)) < nper[t >> 5]);
    if (occ) {
        u32 rc_ = rec[t];
        int st_ = rc_ & 2047, en_ = (rc_ >> 11) & 2047, tb = (int)((rc_ >> 22) & 1u);
        int r = rbase + (t >> 5);
        int root = lab[t];
        atomicMax(&a0[root], 2047 - r);
        atomicMax(&a1[root], r + 1);
        atomicMax(&a2[root], 2048 - st_);
        atomicMax(&a3[root], en_ + 1);
        if (tb) atomicOr(&atx[root], 1);
    }
    __syncthreads();

    // ---- Phase 5: allocate global node ids, write root records ----
    int flag = occ && (lab[t] == t);
    u64 bmask = __ballot(flag);
    int lanepfx = __popcll(bmask & ((1ull << l) - 1ull));
    if (l == 0) wtot[wv] = __popcll(bmask);
    __syncthreads();
    if (t == 0) {
        int s = 0;
        for (int w2 = 0; w2 < 4; ++w2) { woff[w2] = s; s += wtot[w2]; }
        sBase = atomicAdd(&ctrs[1], s);
    }
    __syncthreads();
    if (flag) {
        int node = sBase + woff[wv] + lanepfx;
        if (node < NCAP) {
            nodemap[t] = node;
            int g = node * 6;
            groots[g + 0] = (u32)a0[t];
            groots[g + 1] = (u32)a1[t];
            groots[g + 2] = (u32)a2[t];
            groots[g + 3] = (u32)a3[t];
            groots[g + 4] = (u32)atx[t];
            int r = rbase + (t >> 5);
            groots[g + 5] = (u32)((r << WSHIFT) | (int)(rec[t] & 2047));
        }
    }
    __syncthreads();

    // ---- Phase 6: emit boundary-row runs with global node ids ----
    if (t < SLOTS) {
        int lr = t >> 5, k = t & (RPR - 1);
        if ((lr == 0 || lr == SH - 1) && k < nper[lr]) {
            int side = (lr == 0) ? 0 : 1;
            int o = (strip * 2 + side) * RPR + k;
            brun_se[o] = rec[t];
            brun_id[o] = nodemap[lab[t]];
        }
    }
    if (t == 0) {
        bcnt[strip * 2 + 0] = nper[0];
        bcnt[strip * 2 + 1] = nper[SH - 1];
    }
    __syncthreads();

    // ---- last-block election ----
    if (t == 0) {
        __threadfence();
        sLast = (atomicAdd(&ctrs[0], 1) == NS - 1);
    }
    __syncthreads();
    if (!sLast) return;
    __threadfence();   // acquire other blocks' writes

    // ================= FINAL PHASE (last block, staged in LDS) ===============
    int ncnt = min(GLD(&ctrs[1]), NCAP);
    for (int n = t; n < ncnt; n += 256) {
        flab[n] = n; f0[n] = 0; f1[n] = 0; f2[n] = 0; f3[n] = 0;
        ftx2[n] = 0; fpix[n] = INT_MAX;
    }
    for (int s = t; s < NS * 2; s += 256) sbc[s] = GLD(&bcnt[s]);
    __syncthreads();

    for (int u = t; u < NS * 2 * BSLOT; u += 256) {   // independent staging loads
        int s = u >> 3, k = u & (BSLOT - 1);
        if (k < min(sbc[s], BSLOT)) {
            sse[u] = GLD(&brun_se[s * RPR + k]);
            sid[u] = GLD(&brun_id[s * RPR + k]);
        }
    }
    __syncthreads();

    // joins: strip b last row vs strip b+1 first row
    for (int b2 = t; b2 < NS - 1; b2 += 256) {
        int A = b2 * 2 + 1, B = (b2 + 1) * 2;
        int na = sbc[A], nb = sbc[B];
        if (na <= BSLOT && nb <= BSLOT) {
            int i = 0, j = 0;
            while (i < na && j < nb) {
                u32 ra = sse[A * BSLOT + i], rb = sse[B * BSLOT + j];
                int sa = ra & 2047, ea = (ra >> 11) & 2047;
                int sb2 = rb & 2047, eb2 = (rb >> 11) & 2047;
                if (sa <= eb2 && sb2 <= ea) {
                    int ia = sid[A * BSLOT + i], ib = sid[B * BSLOT + j];
                    if (ia >= 0 && ib >= 0) lmerge(flab, ia, ib);
                }
                if (ea <= eb2) ++i; else ++j;
            }
        } else {   // rare fallback: direct global two-pointer
            int i = 0, j = 0;
            while (i < na && j < nb) {
                u32 ra = GLD(&brun_se[A * RPR + i]), rb = GLD(&brun_se[B * RPR + j]);
                int sa = ra & 2047, ea = (ra >> 11) & 2047;
                int sb2 = rb & 2047, eb2 = (rb >> 11) & 2047;
                if (sa <= eb2 && sb2 <= ea) {
                    int ia = GLD(&brun_id[A * RPR + i]), ib = GLD(&brun_id[B * RPR + j]);
                    if (ia >= 0 && ib >= 0) lmerge(flab, ia, ib);
                }
                if (ea <= eb2) ++i; else ++j;
            }
        }
    }
    __syncthreads();

    #pragma unroll
    for (int pass = 0; pass < 5; ++pass) {     // jump compression
        for (int n = t; n < ncnt; n += 256) {
            int p = flab[n], g = flab[p];
            if (g != p) flab[n] = g;
        }
        __syncthreads();
    }

    // fold root records (independent global loads, LDS atomics)
    for (int n = t; n < ncnt; n += 256) {
        int R = flab[n];
        int g = n * 6;
        atomicMax(&f0[R], (int)GLD(&groots[g + 0]));
        atomicMax(&f1[R], (int)GLD(&groots[g + 1]));
        atomicMax(&f2[R], (int)GLD(&groots[g + 2]));
        atomicMax(&f3[R], (int)GLD(&groots[g + 3]));
        if (GLD(&groots[g + 4])) atomicOr(&ftx2[R], 1);
        atomicMin(&fpix[R], (int)GLD(&groots[g + 5]));
    }
    __syncthreads();

    // emit valid final roots into the memset-zeroed d_out
    for (int n = t; n < ncnt; n += 256) {
        if (flab[n] == n) {
            int ym = 2047 - f0[n], yx = f1[n] - 1;
            int xm = 2048 - f2[n], xx = f3[n] - 1;
            int h = yx - ym, w = xx - xm;
            if (h > 4 && w > 4 && ftx2[n]) {
                int p = fpix[n];
                v4i bb = {ym, xm, h, w};
                obb[p] = bb;
                oval[p] = 1;
            }
        }
    }
}

extern "C" void kernel_launch(void* const* d_in, const int* in_sizes, int n_in,
                              void* d_out, int out_size, void* d_ws, size_t ws_size,
                              hipStream_t stream) {
    const float* x = (const float*)d_in[0];

    // ws layout — every word read this launch is freshly written this launch
    u32* combp   = (u32*)d_ws;                 // NPIX/32
    u32* textp   = combp + NPIX / 32;          // NPIX/32
    u32* brun_se = textp + NPIX / 32;          // NS*2*RPR
    int* brun_id = (int*)(brun_se + NS * 2 * RPR);
    int* bcnt    = brun_id + NS * 2 * RPR;     // NS*2
    int* ctrs    = bcnt + NS * 2;              // [0]=done [1]=gcnt
    u32* groots  = (u32*)(ctrs + 2);           // NCAP*6

    int* obb  = (int*)d_out;
    int* oval = obb + (size_t)NPIX * 4;

    // d_out zeroing via the runtime fill kernel (measured 6.3 TB/s)
    hipMemsetAsync(d_out, 0, (size_t)NPIX * 5 * sizeof(int), stream);
    k_flags<<<NPIX / 256, 256, 0, stream>>>((const float2*)x, (u64*)combp,
                                            (u64*)textp, ctrs);
    k_stripf<<<NS, 256, 0, stream>>>(combp, textp, brun_se, brun_id, bcnt,
                                     groots, ctrs, (v4i*)obb, oval);
}

// Round 12
// 110.951 us; speedup vs baseline: 1.2848x; 1.2848x over previous
//
#include <hip/hip_runtime.h>
#include <climits>
#include <stdint.h>

typedef unsigned int u32;
typedef unsigned long long u64;
typedef int v4i __attribute__((ext_vector_type(4)));

#define HH 1536
#define WW 2048
#define NPIX (HH*WW)        // 3145728
#define WSHIFT 11
#define WPR 64              // 32-bit words per row
#define SH 16               // rows per strip (R9-proven geometry)
#define NS 96               // strips
#define RPR 32              // run slots per row
#define SLOTS (SH*RPR)      // 512
#define NCAP 1024           // global node cap (~150 expected)
#define BSLOT 8             // staged boundary-run slots per side

#define GLD(p) __hip_atomic_load((p), __ATOMIC_RELAXED, __HIP_MEMORY_SCOPE_AGENT)

// ---------------- K1: threshold + pack via ballot (pure streaming read) ------
__global__ void k_flags(const float2* __restrict__ xv,
                        u64* __restrict__ combp64, u64* __restrict__ textp64,
                        int* __restrict__ ctrs) {
    int gid = blockIdx.x * 256 + threadIdx.x;
    float2 f = xv[gid];
    int tx = f.x > 0.4f;
    int cb = tx | (f.y > 0.4f);
    u64 bc = __ballot(cb);
    u64 bt = __ballot(tx);
    if ((threadIdx.x & 63) == 0) {
        combp64[gid >> 6] = bc;
        textp64[gid >> 6] = bt;
    }
    if (gid == 0) { ctrs[0] = 0; ctrs[1] = 0; }   // done, gcnt
}

// ---------------- LDS UF with path halving (R6 lesson) -----------------------
__device__ __forceinline__ int lfind_h(int* L, int x) {
    while (true) {
        int p = L[x];
        if (p == x) return x;
        int g = L[p];
        if (g == p) return p;
        L[x] = g;
        x = g;
    }
}

__device__ __forceinline__ void lmerge(int* L, int a, int b) {
    while (true) {
        a = lfind_h(L, a);
        b = lfind_h(L, b);
        if (a == b) return;
        if (a < b) { int s = a; a = b; b = s; }
        int old = atomicMin(&L[a], b);
        if (old == a) return;
        a = old;
    }
}

// ---------------- K2: strips + final (plain-load staging, acq/rel handoff) ---
// Encoded maxima (>0, LDS 0-init identity): 2047-row, row+1, 2048-start, end+1
__global__ __launch_bounds__(512) void k_stripf(
        const u32* __restrict__ combp, const u32* __restrict__ textp,
        u32* __restrict__ brun_se, int* __restrict__ brun_id,
        u64* __restrict__ bpack, int* __restrict__ bcnt,
        int* __restrict__ groots, int* __restrict__ ctrs,
        v4i* __restrict__ obb, int* __restrict__ oval) {
    __shared__ u32 sb[SH][RPR], eb[SH][RPR];
    __shared__ u32 rec[SLOTS];
    __shared__ int lab[SLOTS];
    __shared__ int a0[SLOTS], a1[SLOTS], a2[SLOTS], a3[SLOTS], atx[SLOTS];
    __shared__ int nodemap[SLOTS];
    __shared__ int nper[SH];
    __shared__ int wtot[8], woff[8];
    __shared__ int sBase, sLast;
    // final-phase staging
    __shared__ u64 sbpk[NS * 2 * BSLOT];
    __shared__ int sbc[NS * 2];
    __shared__ int flab[NCAP];
    __shared__ int f0[NCAP], f1[NCAP], f2[NCAP], f3[NCAP], ftx2[NCAP], fpix[NCAP];

    int strip = blockIdx.x;
    int rbase = strip * SH;
    int t = threadIdx.x;
    int wv = t >> 6, l = t & 63;
    int lr0 = wv * 2;

    // ---- Phase 1: dilate + extract runs, 2 rows per wave ----
    u32 tK[2];
    int nrK[2];
    #pragma unroll
    for (int q = 0; q < 2; ++q) {
        int lr = lr0 + q;
        int r = rbase + lr;
        int base = r * WPR + l;
        u32 c0 = combp[base];
        u32 cm = (r > 0)      ? combp[base - WPR] : 0u;
        u32 cp = (r < HH - 1) ? combp[base + WPR] : 0u;
        u32 v = c0 | cm | cp;
        u32 vl = __shfl_up(v, 1);   if (l == 0)  vl = 0;
        u32 vr = __shfl_down(v, 1); if (l == 63) vr = 0;
        u32 f = v | (v << 1) | (v >> 1) | (vl >> 31) | (vr << 31);
        u32 flw = __shfl_up(f, 1);   if (l == 0)  flw = 0;
        u32 frw = __shfl_down(f, 1); if (l == 63) frw = 0;
        u32 smask = f & ~((f << 1) | (flw >> 31));
        u32 emask = f & ~((f >> 1) | ((frw & 1u) << 31));
        int ns = __popc(smask), ne = __popc(emask);
        int is = ns, ie = ne;
        #pragma unroll
        for (int o = 1; o < 64; o <<= 1) {
            int a = __shfl_up(is, o); if (l >= o) is += a;
            int b = __shfl_up(ie, o); if (l >= o) ie += b;
        }
        int ks = is - ns, ke = ie - ne;
        u32 m = smask; int k = ks;
        while (m) { int b = __ffs(m) - 1; m &= m - 1; if (k < RPR) sb[lr][k] = (u32)(l * 32 + b); ++k; }
        m = emask; k = ke;
        while (m) { int b = __ffs(m) - 1; m &= m - 1; if (k < RPR) eb[lr][k] = (u32)(l * 32 + b); ++k; }
        int nr = __shfl(is, 63);
        nrK[q] = min(nr, RPR);
        tK[q] = textp[base] & f;
        if (l == 0) nper[lr] = nrK[q];
    }
    if (t < SLOTS) {
        lab[t] = t; a0[t] = 0; a1[t] = 0; a2[t] = 0; a3[t] = 0; atx[t] = 0;
        nodemap[t] = -1;
    }
    __syncthreads();

    // ---- Phase 2: per-run txt bit + rec build ----
    #pragma unroll
    for (int q = 0; q < 2; ++q) {
        int lr = lr0 + q;
        int nr = nrK[q];
        u32 txtm = 0;
        for (int kk = 0; kk < nr; ++kk) {
            int st = (int)sb[lr][kk], en = (int)eb[lr][kk];
            int lo = max(st - l * 32, 0), hi = min(en - l * 32, 31);
            u32 mask = 0;
            if (lo <= hi)
                mask = ((hi == 31) ? 0xFFFFFFFFu : ((1u << (hi + 1)) - 1u)) & ~((1u << lo) - 1u);
            int any = __any((tK[q] & mask) != 0);
            txtm |= (any ? 1u : 0u) << kk;
        }
        if (l < nr)
            rec[lr * RPR + l] = sb[lr][l] | (eb[lr][l] << 11) | (((txtm >> l) & 1u) << 22);
    }
    __syncthreads();

    // ---- Phase 3: vertical merges (15 row pairs, two-pointer, all LDS) ----
    if (t < SH - 1) {
        int na = nper[t], nb = nper[t + 1];
        int i = 0, j = 0;
        while (i < na && j < nb) {
            u32 ra = rec[t * RPR + i], rb = rec[(t + 1) * RPR + j];
            int sa = ra & 2047, ea = (ra >> 11) & 2047;
            int sb2 = rb & 2047, eb2 = (rb >> 11) & 2047;
            if (sa <= eb2 && sb2 <= ea) lmerge(lab, t * RPR + i, (t + 1) * RPR + j);
            if (ea <= eb2) ++i; else ++j;
        }
    }
    __syncthreads();

    // ---- Phase 4: jump compression ----
    #pragma unroll
    for (int pass = 0; pass < 6; ++pass) {
        if (t < SLOTS) {
            int p = lab[t], g = lab[p];
            if (g != p) lab[t] = g;
        }
        __syncthreads();
    }

    // ---- Phase 5: fold runs into strip-root accumulators (LDS atomics) ----
    int occ = (t < SLOTS) && ((t & (RPR - 1)) < nper[t >> 5]);
    if (occ) {
        u32 rc_ = rec[t];
        int st_ = rc_ & 2047, en_ = (rc_ >> 11) & 2047, tb = (int)((rc_ >> 22) & 1u);
        int r = rbase + (t >> 5);
        int root = lab[t];
        atomicMax(&a0[root], 2047 - r);
        atomicMax(&a1[root], r + 1);
        atomicMax(&a2[root], 2048 - st_);
        atomicMax(&a3[root], en_ + 1);
        if (tb) atomicOr(&atx[root], 1);
    }
    __syncthreads();

    // ---- Phase 6: allocate global node ids, write root records (stride 8) ---
    int flag = occ && (lab[t] == t);
    u64 bmask = __ballot(flag);
    int lanepfx = __popcll(bmask & ((1ull << l) - 1ull));
    if (l == 0) wtot[wv] = __popcll(bmask);
    __syncthreads();
    if (t == 0) {
        int s = 0;
        for (int w2 = 0; w2 < 8; ++w2) { woff[w2] = s; s += wtot[w2]; }
        sBase = atomicAdd(&ctrs[1], s);
    }
    __syncthreads();
    if (flag) {
        int node = sBase + woff[wv] + lanepfx;
        if (node < NCAP) {
            nodemap[t] = node;
            int g = node * 8;
            int r = rbase + (t >> 5);
            groots[g + 0] = a0[t];
            groots[g + 1] = a1[t];
            groots[g + 2] = a2[t];
            groots[g + 3] = a3[t];
            groots[g + 4] = atx[t];
            groots[g + 5] = (r << WSHIFT) | (int)(rec[t] & 2047);
        }
    }
    __syncthreads();

    // ---- Phase 7: emit boundary runs: packed contiguous + full fallback -----
    if (t < SLOTS) {
        int lr = t >> 5, k = t & (RPR - 1);
        if ((lr == 0 || lr == SH - 1) && k < nper[lr]) {
            int side = (lr == 0) ? 0 : 1;
            int id = nodemap[lab[t]];
            if (k < BSLOT)
                bpack[(strip * 2 + side) * BSLOT + k] =
                    (u64)rec[t] | ((u64)(u32)(id + 1) << 32);
            int o = (strip * 2 + side) * RPR + k;   // full copy for fallback
            brun_se[o] = rec[t];
            brun_id[o] = id;
        }
    }
    if (t == 0) {
        bcnt[strip * 2 + 0] = nper[0];
        bcnt[strip * 2 + 1] = nper[SH - 1];
    }
    __syncthreads();

    // ---- last-block election: release fence + ACQ_REL RMW -------------------
    if (t == 0) {
        __threadfence();                       // release this block's writes
        int old = __hip_atomic_fetch_add(&ctrs[0], 1, __ATOMIC_ACQ_REL,
                                         __HIP_MEMORY_SCOPE_AGENT);
        sLast = (old == NS - 1);               // acquire: L1/L2 invalidated here
    }
    __syncthreads();
    if (!sLast) return;

    // ================= FINAL PHASE (last block; PLAIN pipelined loads) =======
    int ncnt = min(ctrs[1], NCAP);             // plain load post-acquire
    for (int n = t; n < ncnt; n += 512) {
        flab[n] = n; f0[n] = 0; f1[n] = 0; f2[n] = 0; f3[n] = 0;
        ftx2[n] = 0; fpix[n] = INT_MAX;
    }
    for (int s = t; s < NS * 2; s += 512) sbc[s] = bcnt[s];
    // stage packed boundary runs: NS*2*BSLOT = 1536 u64 over 512 thr = 3 iters
    #pragma unroll
    for (int u = t; u < NS * 2 * BSLOT; u += 512) sbpk[u] = bpack[u];
    __syncthreads();

    // joins: strip b last row vs strip b+1 first row
    if (t < NS - 1) {
        int A = t * 2 + 1, B = (t + 1) * 2;
        int na = sbc[A], nb = sbc[B];
        if (na <= BSLOT && nb <= BSLOT) {
            int i = 0, j = 0;
            while (i < na && j < nb) {
                u64 pa = sbpk[A * BSLOT + i], pb = sbpk[B * BSLOT + j];
                u32 ra = (u32)pa, rb = (u32)pb;
                int sa = ra & 2047, ea = (ra >> 11) & 2047;
                int sb2 = rb & 2047, eb2 = (rb >> 11) & 2047;
                if (sa <= eb2 && sb2 <= ea) {
                    int ia = (int)(pa >> 32) - 1, ib = (int)(pb >> 32) - 1;
                    if (ia >= 0 && ib >= 0) lmerge(flab, ia, ib);
                }
                if (ea <= eb2) ++i; else ++j;
            }
        } else {   // rare fallback: full arrays via agent-scope loads
            int i = 0, j = 0;
            while (i < na && j < nb) {
                u32 ra = GLD(&brun_se[A * RPR + i]), rb = GLD(&brun_se[B * RPR + j]);
                int sa = ra & 2047, ea = (ra >> 11) & 2047;
                int sb2 = rb & 2047, eb2 = (rb >> 11) & 2047;
                if (sa <= eb2 && sb2 <= ea) {
                    int ia = GLD(&brun_id[A * RPR + i]), ib = GLD(&brun_id[B * RPR + j]);
                    if (ia >= 0 && ib >= 0) lmerge(flab, ia, ib);
                }
                if (ea <= eb2) ++i; else ++j;
            }
        }
    }
    __syncthreads();

    #pragma unroll
    for (int pass = 0; pass < 5; ++pass) {     // jump compression
        for (int n = t; n < ncnt; n += 512) {
            int p = flab[n], g = flab[p];
            if (g != p) flab[n] = g;
        }
        __syncthreads();
    }

    // fold root records: two dwordx4 plain loads per node, LDS atomics
    for (int n = t; n < ncnt; n += 512) {
        int R = flab[n];
        v4i lo = *(const v4i*)&groots[n * 8];
        v4i hi = *(const v4i*)&groots[n * 8 + 4];
        atomicMax(&f0[R], lo.x);
        atomicMax(&f1[R], lo.y);
        atomicMax(&f2[R], lo.z);
        atomicMax(&f3[R], lo.w);
        if (hi.x) atomicOr(&ftx2[R], 1);
        atomicMin(&fpix[R], hi.y);
    }
    __syncthreads();

    // emit valid final roots into the memset-zeroed d_out
    for (int n = t; n < ncnt; n += 512) {
        if (flab[n] == n) {
            int ym = 2047 - f0[n], yx = f1[n] - 1;
            int xm = 2048 - f2[n], xx = f3[n] - 1;
            int h = yx - ym, w = xx - xm;
            if (h > 4 && w > 4 && ftx2[n]) {
                int p = fpix[n];
                v4i bb = {ym, xm, h, w};
                obb[p] = bb;
                oval[p] = 1;
            }
        }
    }
}

extern "C" void kernel_launch(void* const* d_in, const int* in_sizes, int n_in,
                              void* d_out, int out_size, void* d_ws, size_t ws_size,
                              hipStream_t stream) {
    const float* x = (const float*)d_in[0];

    // ws layout (alignment: groots 16B, bpack 8B; all sizes keep alignment)
    u32* combp   = (u32*)d_ws;                     // NPIX/32 words
    u32* textp   = combp + NPIX / 32;              // NPIX/32
    int* groots  = (int*)(textp + NPIX / 32);      // NCAP*8 (16B-aligned)
    u64* bpack   = (u64*)(groots + NCAP * 8);      // NS*2*BSLOT (8B-aligned)
    u32* brun_se = (u32*)(bpack + NS * 2 * BSLOT); // NS*2*RPR
    int* brun_id = (int*)(brun_se + NS * 2 * RPR); // NS*2*RPR
    int* bcnt    = brun_id + NS * 2 * RPR;         // NS*2
    int* ctrs    = bcnt + NS * 2;                  // [0]=done [1]=gcnt

    int* obb  = (int*)d_out;
    int* oval = obb + (size_t)NPIX * 4;

    hipMemsetAsync(d_out, 0, (size_t)NPIX * 5 * sizeof(int), stream);
    k_flags<<<NPIX / 256, 256, 0, stream>>>((const float2*)x, (u64*)combp,
                                            (u64*)textp, ctrs);
    k_stripf<<<NS, 512, 0, stream>>>(combp, textp, brun_se, brun_id, bpack,
                                     bcnt, groots, ctrs, (v4i*)obb, oval);
}